// Round 3
// baseline (343.108 us; speedup 1.0000x reference)
//
#include <hip/hip_runtime.h>
#include <math.h>

#define NN 8192
#define DD 64
#define SS 4096

// Butterfly reduce: result replicated on all 64 lanes.
__device__ __forceinline__ float wred(float v) {
    #pragma unroll
    for (int o = 1; o < 64; o <<= 1) v += __shfl_xor(v, o);
    return v;
}

// One wave (64 lanes) per block, one sample per block. Grid = SS blocks.
// Small blocks -> deep CU oversubscription -> fast cond!=1 blocks retire and
// are backfilled, auto-balancing the rare heavy (cond==1) adj scans.
__global__ void __launch_bounds__(64) fused_sample_kernel(
        const float* __restrict__ E, const float* __restrict__ Eprev,
        const float* __restrict__ theta, const float* __restrict__ adj,
        const int* __restrict__ j_idx, const int* __restrict__ k_idx,
        const int* __restrict__ nj_idx, const int* __restrict__ i_idx,
        const int* __restrict__ cond, float4* __restrict__ part) {
    int s = blockIdx.x;
    int lane = threadIdx.x;

    int j = j_idx[s], k = k_idx[s], nj = nj_idx[s], i = i_idx[s], c = cond[s];

    // ---- coalesced row gathers: lane d holds element d ----
    float ui  = E[(size_t)i  * DD + lane];
    float uj  = E[(size_t)j  * DD + lane];
    float uk  = E[(size_t)k  * DD + lane];
    float un  = E[(size_t)nj * DD + lane];
    float thk = theta[(size_t)k * DD + lane];

    float dp = uj - uk, dn = un - uk;
    float pos = wred(dp * dp);
    float neg = wred(dn * dn);
    float tik = wred(thk * ui);
    float tjk = wred(thk * uj);
    float dgk = wred(thk * uk);   // diag[k] = theta_k . u_k

    // ---- L_smooth slice: this block covers float2 chunk [s*64, s*64+64) ----
    float sm;
    {
        const float2* a2 = (const float2*)E;
        const float2* b2 = (const float2*)Eprev;
        float2 x = a2[(size_t)s * 64 + lane];
        float2 y = b2[(size_t)s * 64 + lane];
        float dx = x.x - y.x, dy = x.y - y.y;
        sm = wred(dx * dx + dy * dy);
    }

    // ---- C1 product: only condition==1 needs the common-neighbor scan ----
    float prod = 1.0f;   // replicated across lanes
    if (c == 1) {        // wave-uniform branch
        const float4* ri = (const float4*)(adj + (size_t)i * NN);
        const float4* rj = (const float4*)(adj + (size_t)j * NN);
        // 8 outer iterations; each batches 8 independent float4 loads
        // (4 per row) before any ballot/wait -> deep MLP.
        for (int it = 0; it < 8; ++it) {
            float4 A[4], B[4];
            #pragma unroll
            for (int u = 0; u < 4; ++u) {
                A[u] = ri[(it * 4 + u) * 64 + lane];
                B[u] = rj[(it * 4 + u) * 64 + lane];
            }
            #pragma unroll
            for (int u = 0; u < 4; ++u) {
                float av[4] = {A[u].x, A[u].y, A[u].z, A[u].w};
                float bv[4] = {B[u].x, B[u].y, B[u].z, B[u].w};
                #pragma unroll
                for (int q = 0; q < 4; ++q) {
                    unsigned long long m = __ballot(av[q] > 0.f && bv[q] > 0.f);
                    while (m) {   // rare: ~0.13 hits per sample on average
                        int src = __ffsll((unsigned long long)m) - 1;
                        m &= m - 1;
                        float ai = __shfl(av[q], src);
                        float aj = __shfl(bv[q], src);
                        int l = ((it * 4 + u) * 64 + src) * 4 + q;
                        float th = theta[(size_t)l * DD + lane];
                        float ul = E[(size_t)l * DD + lane];
                        float r1 = wred(th * (ul - ui));   // diag[l]-theta_l.u_i
                        float r2 = wred(th * (ul - uj));   // diag[l]-theta_l.u_j
                        float dl = ai * r1 + aj * r2;
                        float P = (dl < -100.f) ? 0.f : 1.f / (1.f + __expf(-dl));
                        prod *= (1.f - P);
                    }
                }
            }
        }
    }

    if (lane == 0) {
        float lsh = fmaxf(pos - neg + 1.0f, 0.f);

        float aik = adj[(size_t)i * NN + k];
        float ajk = adj[(size_t)j * NN + k];
        float dot_k = aik * (dgk - tik) + ajk * (dgk - tjk);

        float x = -dot_k;   // softplus(-dot_k)
        float logp = fmaxf(x, 0.f) + log1pf(expf(-fabsf(x)));

        float ltr;
        if (c == -1) {
            ltr = 0.f;
        } else if (c == 0) {
            ltr = logp + dot_k;
        } else {
            float C1 = 1.f - prod;
            float C0 = (dot_k < -100.f) ? 0.f : 1.f / (1.f + expf(-dot_k));
            ltr = logp + (1.f - C0 / (C1 + 1e-6f));
        }
        part[s] = make_float4(lsh, ltr, sm, 0.f);
    }
}

// Single block: reduce 4096 float4 partials in double, emit the scalar loss.
__global__ void __launch_bounds__(256) final_reduce_kernel(
        const float4* __restrict__ part, float* __restrict__ out) {
    double lsh = 0.0, ltr = 0.0, sm = 0.0;
    for (int t = threadIdx.x; t < SS; t += 256) {
        float4 p = part[t];
        lsh += (double)p.x;
        ltr += (double)p.y;
        sm  += (double)p.z;
    }
    #pragma unroll
    for (int o = 32; o; o >>= 1) {
        lsh += __shfl_down(lsh, o);
        ltr += __shfl_down(ltr, o);
        sm  += __shfl_down(sm, o);
    }
    __shared__ double sh[3][4];
    int lane = threadIdx.x & 63, wv = threadIdx.x >> 6;
    if (lane == 0) { sh[0][wv] = lsh; sh[1][wv] = ltr; sh[2][wv] = sm; }
    __syncthreads();
    if (threadIdx.x == 0) {
        double L = (sh[0][0] + sh[0][1] + sh[0][2] + sh[0][3])
                 + 0.1 * (sh[1][0] + sh[1][1] + sh[1][2] + sh[1][3])
                 + 0.1 * (double)SS * (sh[2][0] + sh[2][1] + sh[2][2] + sh[2][3]);
        out[0] = (float)L;
    }
}

extern "C" void kernel_launch(void* const* d_in, const int* in_sizes, int n_in,
                              void* d_out, int out_size, void* d_ws, size_t ws_size,
                              hipStream_t stream) {
    const float* emb_t    = (const float*)d_in[0];
    const float* emb_prev = (const float*)d_in[1];
    const float* theta    = (const float*)d_in[2];
    const float* adj      = (const float*)d_in[3];
    const int*   j_idx    = (const int*)d_in[4];
    const int*   k_idx    = (const int*)d_in[5];
    const int*   nj_idx   = (const int*)d_in[6];
    const int*   i_idx    = (const int*)d_in[7];
    const int*   cond     = (const int*)d_in[8];
    float* out = (float*)d_out;

    float4* part = (float4*)d_ws;   // 4096 * 16 B = 64 KiB

    fused_sample_kernel<<<SS, 64, 0, stream>>>(
        emb_t, emb_prev, theta, adj, j_idx, k_idx, nj_idx, i_idx, cond, part);
    final_reduce_kernel<<<1, 256, 0, stream>>>(part, out);
}

// Round 4
// 340.565 us; speedup vs baseline: 1.0075x; 1.0075x over previous
//
#include <hip/hip_runtime.h>
#include <math.h>

#define NN 8192
#define DD 64
#define SS 4096
#define CAP 512   // max nonzeros collected from row i (row degree ~33 +/- 6)

// Butterfly reduce: result replicated on all 64 lanes.
__device__ __forceinline__ float wred(float v) {
    #pragma unroll
    for (int o = 1; o < 64; o <<= 1) v += __shfl_xor(v, o);
    return v;
}

// ws layout: [0,16) counters (heavy, light), [16, 16+4*SS) order[],
// then float4 part[SS] (offset 16400, 16-aligned).

// Order samples heavy-first (cond==1 first). Wave-aggregated atomics.
__global__ void __launch_bounds__(256) partition_kernel(
        const int* __restrict__ cond, int* __restrict__ counters,
        int* __restrict__ order) {
    int t = blockIdx.x * 256 + threadIdx.x;
    if (t < SS) {
        int c = cond[t];
        int p;
        if (c == 1) p = atomicAdd(&counters[0], 1);
        else        p = SS - 1 - atomicAdd(&counters[1], 1);
        order[p] = t;
    }
}

// One wave (64 lanes) per block, one sample per block, heavy-first order.
__global__ void __launch_bounds__(64) fused_sample_kernel(
        const float* __restrict__ E, const float* __restrict__ Eprev,
        const float* __restrict__ theta, const float* __restrict__ adj,
        const int* __restrict__ j_idx, const int* __restrict__ k_idx,
        const int* __restrict__ nj_idx, const int* __restrict__ i_idx,
        const int* __restrict__ cond, const int* __restrict__ order,
        float4* __restrict__ part) {
    int s = order[blockIdx.x];
    int lane = threadIdx.x;

    int j = j_idx[s], k = k_idx[s], nj = nj_idx[s], i = i_idx[s], c = cond[s];

    // ---- coalesced row gathers: lane d holds element d ----
    float ui  = E[(size_t)i  * DD + lane];
    float uj  = E[(size_t)j  * DD + lane];
    float uk  = E[(size_t)k  * DD + lane];
    float un  = E[(size_t)nj * DD + lane];
    float thk = theta[(size_t)k * DD + lane];

    // issue dot_k's adj loads early (uniform address -> broadcast)
    float aik = adj[(size_t)i * NN + k];
    float ajk = adj[(size_t)j * NN + k];

    float dp = uj - uk, dn = un - uk;
    float pos = wred(dp * dp);
    float neg = wred(dn * dn);
    float tik = wred(thk * ui);
    float tjk = wred(thk * uj);
    float dgk = wred(thk * uk);   // diag[k] = theta_k . u_k

    // ---- L_smooth slice: this block covers float2 chunk [s*64, s*64+64) ----
    float sm;
    {
        const float2* a2 = (const float2*)E;
        const float2* b2 = (const float2*)Eprev;
        float2 x = a2[(size_t)s * 64 + lane];
        float2 y = b2[(size_t)s * 64 + lane];
        float dx = x.x - y.x, dy = x.y - y.y;
        sm = wred(dx * dx + dy * dy);
    }

    // ---- C1 product (cond==1 only): scan row i, gather row j at hits ----
    float prod = 1.0f;
    if (c == 1) {   // wave-uniform branch
        __shared__ int   idx_sh[CAP];
        __shared__ float aval_sh[CAP];
        __shared__ float bval_sh[CAP];

        const float4* ri = (const float4*)(adj + (size_t)i * NN);
        int cnt = 0;   // wave-uniform

        // Phase A: stream row i (32 KB), append nonzero columns to LDS list.
        for (int it = 0; it < 4; ++it) {   // 4 batches of 8 float4/lane
            float4 A[8];
            #pragma unroll
            for (int u = 0; u < 8; ++u)
                A[u] = ri[(it * 8 + u) * 64 + lane];
            #pragma unroll
            for (int u = 0; u < 8; ++u) {
                float av[4] = {A[u].x, A[u].y, A[u].z, A[u].w};
                #pragma unroll
                for (int q = 0; q < 4; ++q) {
                    bool hit = av[q] > 0.f;
                    unsigned long long m = __ballot(hit);
                    if (hit) {
                        int off = __popcll(m & ((1ull << lane) - 1ull));
                        int p = cnt + off;
                        if (p < CAP) {
                            idx_sh[p]  = ((it * 8 + u) * 64 + lane) * 4 + q;
                            aval_sh[p] = av[q];
                        }
                    }
                    cnt += __popcll(m);
                }
            }
        }
        if (cnt > CAP) cnt = CAP;
        __syncthreads();

        // Phase B: gather adj[j][l] at the collected columns (~33 lines).
        for (int p = lane; p < cnt; p += 64)
            bval_sh[p] = adj[(size_t)j * NN + idx_sh[p]];
        __syncthreads();

        // Phase C: per common neighbor, cooperative D=64 dot products.
        for (int p = 0; p < cnt; ++p) {
            float bj = bval_sh[p];
            if (bj > 0.f) {
                int l = idx_sh[p];
                float ai = aval_sh[p];
                float th = theta[(size_t)l * DD + lane];
                float ul = E[(size_t)l * DD + lane];
                float r1 = wred(th * (ul - ui));   // diag[l] - theta_l.u_i
                float r2 = wred(th * (ul - uj));   // diag[l] - theta_l.u_j
                float dl = ai * r1 + bj * r2;
                float P = (dl < -100.f) ? 0.f : 1.f / (1.f + __expf(-dl));
                prod *= (1.f - P);
            }
        }
    }

    if (lane == 0) {
        float lsh = fmaxf(pos - neg + 1.0f, 0.f);

        float dot_k = aik * (dgk - tik) + ajk * (dgk - tjk);

        float x = -dot_k;   // softplus(-dot_k)
        float logp = fmaxf(x, 0.f) + log1pf(expf(-fabsf(x)));

        float ltr;
        if (c == -1) {
            ltr = 0.f;
        } else if (c == 0) {
            ltr = logp + dot_k;
        } else {
            float C1 = 1.f - prod;
            float C0 = (dot_k < -100.f) ? 0.f : 1.f / (1.f + expf(-dot_k));
            ltr = logp + (1.f - C0 / (C1 + 1e-6f));
        }
        part[s] = make_float4(lsh, ltr, sm, 0.f);
    }
}

// Single block: reduce 4096 float4 partials in double, emit the scalar loss.
__global__ void __launch_bounds__(256) final_reduce_kernel(
        const float4* __restrict__ part, float* __restrict__ out) {
    double lsh = 0.0, ltr = 0.0, sm = 0.0;
    for (int t = threadIdx.x; t < SS; t += 256) {
        float4 p = part[t];
        lsh += (double)p.x;
        ltr += (double)p.y;
        sm  += (double)p.z;
    }
    #pragma unroll
    for (int o = 32; o; o >>= 1) {
        lsh += __shfl_down(lsh, o);
        ltr += __shfl_down(ltr, o);
        sm  += __shfl_down(sm, o);
    }
    __shared__ double sh[3][4];
    int lane = threadIdx.x & 63, wv = threadIdx.x >> 6;
    if (lane == 0) { sh[0][wv] = lsh; sh[1][wv] = ltr; sh[2][wv] = sm; }
    __syncthreads();
    if (threadIdx.x == 0) {
        double L = (sh[0][0] + sh[0][1] + sh[0][2] + sh[0][3])
                 + 0.1 * (sh[1][0] + sh[1][1] + sh[1][2] + sh[1][3])
                 + 0.1 * (double)SS * (sh[2][0] + sh[2][1] + sh[2][2] + sh[2][3]);
        out[0] = (float)L;
    }
}

extern "C" void kernel_launch(void* const* d_in, const int* in_sizes, int n_in,
                              void* d_out, int out_size, void* d_ws, size_t ws_size,
                              hipStream_t stream) {
    const float* emb_t    = (const float*)d_in[0];
    const float* emb_prev = (const float*)d_in[1];
    const float* theta    = (const float*)d_in[2];
    const float* adj      = (const float*)d_in[3];
    const int*   j_idx    = (const int*)d_in[4];
    const int*   k_idx    = (const int*)d_in[5];
    const int*   nj_idx   = (const int*)d_in[6];
    const int*   i_idx    = (const int*)d_in[7];
    const int*   cond     = (const int*)d_in[8];
    float* out = (float*)d_out;

    int*    counters = (int*)d_ws;                       // 2 ints (+pad to 16)
    int*    order    = (int*)((char*)d_ws + 16);         // SS ints
    float4* part     = (float4*)((char*)d_ws + 16 + 4 * SS);  // 16-aligned

    hipMemsetAsync(d_ws, 0, 16, stream);
    partition_kernel<<<SS / 256, 256, 0, stream>>>(cond, counters, order);
    fused_sample_kernel<<<SS, 64, 0, stream>>>(
        emb_t, emb_prev, theta, adj, j_idx, k_idx, nj_idx, i_idx, cond,
        order, part);
    final_reduce_kernel<<<1, 256, 0, stream>>>(part, out);
}